// Round 8
// baseline (78.018 us; speedup 1.0000x reference)
//
#include <hip/hip_runtime.h>
#include <stdint.h>

// ContrastiveLoss: mean over all pairs of (same-label ? d2 : relu(1-dist)^2)
// z: [8192,128] fp32, labels: [8192] int32. Output: 1 fp32 scalar.
//
// R8: attack barrier-convoy serialization (loss ~13us vs ~4-5us pipe floor;
// only 3 independent blocks/CU at 512 thr). Split each 128x128 tile into two
// 64x128 half-tiles: 4160 blocks x 256 thr (4 waves, 2x2, same 2x4-frag
// wave code), LDS ~26KB, __launch_bounds__(256,6) -> 6 blocks/CU = 6
// independent stage->barrier->compute streams with 4-wave barriers.
// Cost: B-panels staged twice (+50% DMA, L2-resident zb = 1MB).
// Kept (counter-verified): baked granule swizzle (conflicts 0), linear
// global_load_lds staging, deferred single wave-vote epilogue, separate
// 2us reduce kernel (NO device-scope fences - R6's 10x lesson).

#define NROWS 8192
#define DIMK  128
#define NB    64                     // 8192 / 128
#define NPAIR (NB * (NB + 1) / 2)    // 2080 upper-triangle 128x128 pairs
#define NBLK  (NPAIR * 2)            // 4160 half-tile blocks

typedef __attribute__((ext_vector_type(4))) float f32x4;

#define AS_GLOBAL __attribute__((address_space(1)))
#define AS_LDS    __attribute__((address_space(3)))

// Convert z -> fp8 e4m3 with granule-swizzled rows: logical k lives in
// granule g = ((k>>3)&3)<<2 | (k>>5) (the 8B MFMA operand for quad q, step
// ks), stored at byte pos ((g ^ (row&15)) << 3) + (k&7). Dot-invariant.
// Also: per-row sum of squares of ROUNDED values (diagonal d2 == 0 exactly).
__global__ __launch_bounds__(256) void prep_kernel(
    const float* __restrict__ z, unsigned char* __restrict__ zb,
    float* __restrict__ sq) {
  int tid = threadIdx.x;
  int row = (blockIdx.x << 3) + (tid >> 5);          // 8 rows per block
  int c32 = tid & 31;                                // 32 lanes per row
  float4 x = ((const float4*)(z + (size_t)row * DIMK))[c32];
  int u = __builtin_amdgcn_cvt_pk_fp8_f32(x.x, x.y, 0, false);
  u     = __builtin_amdgcn_cvt_pk_fp8_f32(x.z, x.w, u, true);
  float r0 = __builtin_amdgcn_cvt_f32_fp8(u, 0);
  float r1 = __builtin_amdgcn_cvt_f32_fp8(u, 1);
  float r2 = __builtin_amdgcn_cvt_f32_fp8(u, 2);
  float r3 = __builtin_amdgcn_cvt_f32_fp8(u, 3);
  float s = (r0 * r0 + r1 * r1) + (r2 * r2 + r3 * r3);
  int k0 = c32 << 2;                                 // logical k of byte 0
  int g  = (((k0 >> 3) & 3) << 2) | (k0 >> 5);       // granule index
  int p  = ((g ^ (row & 15)) << 3) + (k0 & 7);       // 4B-aligned
  *(uint32_t*)(zb + (size_t)row * DIMK + p) = (uint32_t)u;
  #pragma unroll
  for (int off = 16; off; off >>= 1) s += __shfl_down(s, off, 32);
  if (c32 == 0) sq[row] = s;
}

// One block = one 64x128 half-tile of z.z^T (pair (bi,bj) upper triangle,
// half h selects rows bi*128+h*64..+64; cols bj*128..+128).
// 256 threads = 4 waves in 2x2 (wm,wn in 0..1); each wave 2x4 frags of
// 16x16x32 fp8_fp8 over its 32x64 sub-tile. A tile 8KB + B tile 16KB,
// staged as LINEAR copies (swizzle baked in zb); ds_read_b64 conflict-free.
__global__ __launch_bounds__(256, 6) void loss_kernel(
    const unsigned char* __restrict__ zb, const float* __restrict__ sq,
    const int* __restrict__ labels, float* __restrict__ partials) {
  __shared__ __align__(16) unsigned char ldsA[8192];
  __shared__ __align__(16) unsigned char ldsB[16384];
  __shared__ __align__(16) float sqAl[64];
  __shared__ __align__(16) float sqBl[128];
  __shared__ __align__(16) int   laAl[64];
  __shared__ __align__(16) int   laBl[128];
  __shared__ float red[4];

  int tid = threadIdx.x, lane = tid & 63, wave = tid >> 6;

  // ---- decode: bid -> pair t (triangular, bi <= bj) + half h ----
  int bid = blockIdx.x;
  int t = bid >> 1, h = bid & 1;
  #define TRI(rr) ((rr) * NB - ((rr) * ((rr) - 1)) / 2)
  int r = (int)(((float)(2 * NB + 1) -
                 sqrtf((float)((2 * NB + 1) * (2 * NB + 1) - 8 * t))) * 0.5f);
  if (r < 0) r = 0; if (r > NB - 1) r = NB - 1;
  while (TRI(r + 1) <= t) ++r;
  while (TRI(r) > t) --r;
  int bi = r, bj = t - TRI(r) + r;
  int row0 = (bi << 7) + (h << 6);                   // 64-row panel start
  int col0 = (bj << 7);                              // 128-col panel start

  // ---- stage tiles: linear copies. A: 512 chunks, B: 1024 chunks ----
  const unsigned char* Ab = zb + (size_t)row0 * DIMK;
  const unsigned char* Bb = zb + (size_t)col0 * DIMK;
  #pragma unroll
  for (int it = 0; it < 2; ++it) {
    int L0 = (it << 8) + (wave << 6);                // wave-uniform
    __builtin_amdgcn_global_load_lds(
        (const AS_GLOBAL void*)(uintptr_t)(Ab + (size_t)(L0 + lane) * 16),
        (AS_LDS void*)(uintptr_t)(ldsA + (size_t)L0 * 16), 16, 0, 0);
  }
  #pragma unroll
  for (int it = 0; it < 4; ++it) {
    int L0 = (it << 8) + (wave << 6);                // wave-uniform
    __builtin_amdgcn_global_load_lds(
        (const AS_GLOBAL void*)(uintptr_t)(Bb + (size_t)(L0 + lane) * 16),
        (AS_LDS void*)(uintptr_t)(ldsB + (size_t)L0 * 16), 16, 0, 0);
  }
  // ---- stage sq + labels for this block's rows/cols into LDS ----
  if (tid < 64) {
    sqAl[tid] = sq[row0 + tid];
    laAl[tid] = labels[row0 + tid];
  } else if (tid < 192) {
    int t2 = tid - 64;
    sqBl[t2] = sq[col0 + t2];
    laBl[t2] = labels[col0 + t2];
  }
  asm volatile("s_waitcnt vmcnt(0)" ::: "memory");
  __syncthreads();

  // ---- MFMA: per-ks b64 frag loads, 8 MFMAs per ks ----
  int wm = wave >> 1, wn = wave & 1;
  int lc = lane & 15;                                // frag row (A) / col (out)
  int q  = lane >> 4;                                // quad: k-granule select
  f32x4 acc[2][4] = {};
  #pragma unroll
  for (int ks = 0; ks < 4; ++ks) {
    int so = ((((q << 2) | ks) ^ lc) << 3);          // swizzled slot offset
    long a0 = *(const long*)(ldsA + ((wm << 5)      + lc) * 128 + so);
    long a1 = *(const long*)(ldsA + ((wm << 5) + 16 + lc) * 128 + so);
    long b0 = *(const long*)(ldsB + ((wn << 6)      + lc) * 128 + so);
    long b1 = *(const long*)(ldsB + ((wn << 6) + 16 + lc) * 128 + so);
    long b2 = *(const long*)(ldsB + ((wn << 6) + 32 + lc) * 128 + so);
    long b3 = *(const long*)(ldsB + ((wn << 6) + 48 + lc) * 128 + so);
    acc[0][0] = __builtin_amdgcn_mfma_f32_16x16x32_fp8_fp8(a0, b0, acc[0][0], 0, 0, 0);
    acc[0][1] = __builtin_amdgcn_mfma_f32_16x16x32_fp8_fp8(a0, b1, acc[0][1], 0, 0, 0);
    acc[0][2] = __builtin_amdgcn_mfma_f32_16x16x32_fp8_fp8(a0, b2, acc[0][2], 0, 0, 0);
    acc[0][3] = __builtin_amdgcn_mfma_f32_16x16x32_fp8_fp8(a0, b3, acc[0][3], 0, 0, 0);
    acc[1][0] = __builtin_amdgcn_mfma_f32_16x16x32_fp8_fp8(a1, b0, acc[1][0], 0, 0, 0);
    acc[1][1] = __builtin_amdgcn_mfma_f32_16x16x32_fp8_fp8(a1, b1, acc[1][1], 0, 0, 0);
    acc[1][2] = __builtin_amdgcn_mfma_f32_16x16x32_fp8_fp8(a1, b2, acc[1][2], 0, 0, 0);
    acc[1][3] = __builtin_amdgcn_mfma_f32_16x16x32_fp8_fp8(a1, b3, acc[1][3], 0, 0, 0);
  }

  // ---- epilogue: branchless fast pass + ONE deferred vote ----
  // C/D layout (shape-determined): col = lane&15, row = (lane>>4)*4 + reg.
  // If every d2 in this wave's outputs >= 1: non-eq term EXACTLY 0, eq term
  // exactly d2. Else (diagonal-touching waves only) redo on exact slow path.
  int r0 = q << 2;
  float sn_[4]; int ln_[4];
  #pragma unroll
  for (int j = 0; j < 4; ++j) {
    int n = (wn << 6) + (j << 4) + lc;
    sn_[j] = sqBl[n]; ln_[j] = laBl[n];
  }
  float ps0 = 0.f, ps1 = 0.f, ps2 = 0.f, ps3 = 0.f;
  float mnall = 1e30f;
  #pragma unroll
  for (int i = 0; i < 2; ++i) {
    int mb = (wm << 5) + (i << 4) + r0;
    f32x4 sm4 = *(const f32x4*)&sqAl[mb];
    int4  lm4 = *(const int4*)&laAl[mb];
    #pragma unroll
    for (int j = 0; j < 4; ++j) {
      float d0  = fmaf(-2.f, acc[i][j][0], sm4[0] + sn_[j]);
      float d1  = fmaf(-2.f, acc[i][j][1], sm4[1] + sn_[j]);
      float d2_ = fmaf(-2.f, acc[i][j][2], sm4[2] + sn_[j]);
      float d3  = fmaf(-2.f, acc[i][j][3], sm4[3] + sn_[j]);
      mnall = fminf(mnall, fminf(fminf(d0, d1), fminf(d2_, d3)));
      ps0 += (lm4.x == ln_[j]) ? d0  : 0.f;
      ps1 += (lm4.y == ln_[j]) ? d1  : 0.f;
      ps2 += (lm4.z == ln_[j]) ? d2_ : 0.f;
      ps3 += (lm4.w == ln_[j]) ? d3  : 0.f;
    }
  }
  if (__builtin_expect(__any(mnall < 1.f), 0)) {
    // exact slow path: recompute all outputs (acc still live)
    ps0 = ps1 = ps2 = ps3 = 0.f;
    #pragma unroll
    for (int i = 0; i < 2; ++i) {
      int mb = (wm << 5) + (i << 4) + r0;
      f32x4 sm4 = *(const f32x4*)&sqAl[mb];
      int4  lm4 = *(const int4*)&laAl[mb];
      #pragma unroll
      for (int j = 0; j < 4; ++j) {
        float dc, tt;
        dc = fmaxf(fmaf(-2.f, acc[i][j][0], sm4[0] + sn_[j]), 0.f);
        tt = fmaxf(1.f - sqrtf(dc), 0.f);
        ps0 += (lm4.x == ln_[j]) ? dc : tt * tt;
        dc = fmaxf(fmaf(-2.f, acc[i][j][1], sm4[1] + sn_[j]), 0.f);
        tt = fmaxf(1.f - sqrtf(dc), 0.f);
        ps1 += (lm4.y == ln_[j]) ? dc : tt * tt;
        dc = fmaxf(fmaf(-2.f, acc[i][j][2], sm4[2] + sn_[j]), 0.f);
        tt = fmaxf(1.f - sqrtf(dc), 0.f);
        ps2 += (lm4.z == ln_[j]) ? dc : tt * tt;
        dc = fmaxf(fmaf(-2.f, acc[i][j][3], sm4[3] + sn_[j]), 0.f);
        tt = fmaxf(1.f - sqrtf(dc), 0.f);
        ps3 += (lm4.w == ln_[j]) ? dc : tt * tt;
      }
    }
  }
  float psum = (ps0 + ps1) + (ps2 + ps3);
  float w = (bi == bj) ? 1.f : 2.f;                  // symmetry weight
  psum *= w * (1.f / (8192.f * 8192.f));             // 2^-26, exact

  // ---- block reduction -> partials[bid] (plain store, no fences) ----
  #pragma unroll
  for (int off = 32; off; off >>= 1) psum += __shfl_down(psum, off);
  if (lane == 0) red[wave] = psum;
  __syncthreads();
  if (tid == 0)
    partials[bid] = (red[0] + red[1]) + (red[2] + red[3]);
}

// Sum NBLK partials -> out[0]. One block.
__global__ __launch_bounds__(256) void reduce_kernel(
    const float* __restrict__ partials, float* __restrict__ out) {
  int tid = threadIdx.x, lane = tid & 63, wave = tid >> 6;
  float s = 0.f;
  for (int k = tid; k < NBLK; k += 256) s += partials[k];
  #pragma unroll
  for (int off = 32; off; off >>= 1) s += __shfl_down(s, off);
  __shared__ float red[4];
  if (lane == 0) red[wave] = s;
  __syncthreads();
  if (tid == 0) out[0] = red[0] + red[1] + red[2] + red[3];
}

extern "C" void kernel_launch(void* const* d_in, const int* in_sizes, int n_in,
                              void* d_out, int out_size, void* d_ws, size_t ws_size,
                              hipStream_t stream) {
  const float* z      = (const float*)d_in[0];
  const int*   labels = (const int*)d_in[1];
  float*       out    = (float*)d_out;
  unsigned char* zb   = (unsigned char*)d_ws;                        // 1 MB
  char* p = (char*)d_ws + (size_t)NROWS * DIMK;
  float* sq       = (float*)p;                                       // 32 KB
  float* partials = (float*)(p + NROWS * 4);                         // ~17 KB

  prep_kernel<<<NROWS / 8, 256, 0, stream>>>(z, zb, sq);
  loss_kernel<<<NBLK, 256, 0, stream>>>(zb, sq, labels, partials);
  reduce_kernel<<<1, 256, 0, stream>>>(partials, out);
}

// Round 9
// 73.029 us; speedup vs baseline: 1.0683x; 1.0683x over previous
//
#include <hip/hip_runtime.h>
#include <stdint.h>

// ContrastiveLoss: mean over all pairs of (same-label ? d2 : relu(1-dist)^2)
// z: [8192,128] fp32, labels: [8192] int32. Output: 1 fp32 scalar.
//
// R9: persistent double-buffered pipeline. R8 falsified the convoy theory
// (6 streams/CU regressed); model that fits R4/R7/R8: per-block fixed cost
// (cold stage->vmcnt(0) latency + launch/decode/reduce) * block count.
// So: 512 persistent blocks x ~4 tiles each, LDS dbuf (2x32KB + 2x2KB
// sq/labels), prefetch tile i+1 issued right AFTER the barrier, so the
// barrier's implicit vmcnt(0) drain is free (vmcnt already 0) and tile
// i+1's DMA flies during tile i's compute. psum accumulates in registers
// across tiles (no per-tile reduction; exactly 5 VMEM ops/tile/wave).
// Kept (counter-verified): baked granule swizzle (conflicts 0), linear
// global_load_lds staging, deferred single wave-vote epilogue, separate
// reduce kernel (NO device-scope fences - R6's 10x lesson).

#define NROWS 8192
#define DIMK  128
#define NB    64                     // 8192 / 128
#define NTILE (NB * (NB + 1) / 2)    // 2080 upper-triangle tiles
#define NPERS 512                    // persistent blocks (2 per CU)

typedef __attribute__((ext_vector_type(4))) float f32x4;

#define AS_GLOBAL __attribute__((address_space(1)))
#define AS_LDS    __attribute__((address_space(3)))

// Convert z -> fp8 e4m3 with granule-swizzled rows: logical k lives in
// granule g = ((k>>3)&3)<<2 | (k>>5), stored at byte ((g^(row&15))<<3)+(k&7).
// Dot-invariant. Also per-row sum of squares of ROUNDED values (diag d2==0).
__global__ __launch_bounds__(256) void prep_kernel(
    const float* __restrict__ z, unsigned char* __restrict__ zb,
    float* __restrict__ sq) {
  int tid = threadIdx.x;
  int row = (blockIdx.x << 3) + (tid >> 5);          // 8 rows per block
  int c32 = tid & 31;                                // 32 lanes per row
  float4 x = ((const float4*)(z + (size_t)row * DIMK))[c32];
  int u = __builtin_amdgcn_cvt_pk_fp8_f32(x.x, x.y, 0, false);
  u     = __builtin_amdgcn_cvt_pk_fp8_f32(x.z, x.w, u, true);
  float r0 = __builtin_amdgcn_cvt_f32_fp8(u, 0);
  float r1 = __builtin_amdgcn_cvt_f32_fp8(u, 1);
  float r2 = __builtin_amdgcn_cvt_f32_fp8(u, 2);
  float r3 = __builtin_amdgcn_cvt_f32_fp8(u, 3);
  float s = (r0 * r0 + r1 * r1) + (r2 * r2 + r3 * r3);
  int k0 = c32 << 2;                                 // logical k of byte 0
  int g  = (((k0 >> 3) & 3) << 2) | (k0 >> 5);       // granule index
  int p  = ((g ^ (row & 15)) << 3) + (k0 & 7);       // 4B-aligned
  *(uint32_t*)(zb + (size_t)row * DIMK + p) = (uint32_t)u;
  #pragma unroll
  for (int off = 16; off; off >>= 1) s += __shfl_down(s, off, 32);
  if (c32 == 0) sq[row] = s;
}

__device__ __forceinline__ void decode_tile(int t, int& bi, int& bj) {
  #define TRI(rr) ((rr) * NB - ((rr) * ((rr) - 1)) / 2)
  int r = (int)(((float)(2 * NB + 1) -
                 sqrtf((float)((2 * NB + 1) * (2 * NB + 1) - 8 * t))) * 0.5f);
  if (r < 0) r = 0; if (r > NB - 1) r = NB - 1;
  while (TRI(r + 1) <= t) ++r;
  while (TRI(r) > t) --r;
  bi = r; bj = t - TRI(r) + r;
}

// Persistent: 512 blocks x 512 thr (8 waves, 4x2); block b computes tiles
// b, b+512, ... with double-buffered staging. Each tile: A panel 16KB +
// B panel 16KB (linear copy; swizzle baked in zb) + 2KB sq/labels.
__global__ __launch_bounds__(512, 4) void loss_kernel(
    const unsigned char* __restrict__ zb, const float* __restrict__ sq,
    const int* __restrict__ labels, float* __restrict__ partials) {
  __shared__ __align__(16) unsigned char buf[2][32768];   // [A 16K | B 16K]
  __shared__ __align__(16) unsigned char sqlab[2][2048];  // [sqA|laA|sqB|laB]
  __shared__ float red[8];

  int tid = threadIdx.x, lane = tid & 63, wave = tid >> 6;
  int wm = wave >> 1, wn = wave & 1;
  int lc = lane & 15;                                // frag row (A)/col (out)
  int q  = lane >> 4;                                // quad: k-granule select

  // sq/label staging role for this wave (one masked DMA per tile):
  //   w0,w1->sqA halves; w2,w3->laA; w4,w5->sqB; w6,w7->laB
  int sl_isB  = wave >> 2;
  int sl_isLa = (wave >> 1) & 1;
  int sl_half = wave & 1;

  float psum_acc = 0.f;

  int b = blockIdx.x;
  int bi, bj;
  decode_tile(b, bi, bj);

  // ---- prologue: stage tile b into buffer 0 ----
  {
    const unsigned char* Ab = zb + (((size_t)bi << 7) * DIMK);
    const unsigned char* Bb = zb + (((size_t)bj << 7) * DIMK);
    #pragma unroll
    for (int it = 0; it < 2; ++it) {
      int L0 = (it << 9) + (wave << 6);
      __builtin_amdgcn_global_load_lds(
          (const AS_GLOBAL void*)(uintptr_t)(Ab + (size_t)(L0 + lane) * 16),
          (AS_LDS void*)(uintptr_t)(&buf[0][(size_t)L0 * 16]), 16, 0, 0);
      __builtin_amdgcn_global_load_lds(
          (const AS_GLOBAL void*)(uintptr_t)(Bb + (size_t)(L0 + lane) * 16),
          (AS_LDS void*)(uintptr_t)(&buf[0][16384 + (size_t)L0 * 16]), 16, 0, 0);
    }
    const char* p0 = sl_isLa ? (const char*)labels : (const char*)sq;
    const char* src = p0 + ((size_t)((sl_isB ? bj : bi) << 7) << 2)
                         + (sl_half << 8);
    if (lane < 16)
      __builtin_amdgcn_global_load_lds(
          (const AS_GLOBAL void*)(uintptr_t)(src + lane * 16),
          (AS_LDS void*)(uintptr_t)(&sqlab[0][wave << 8]), 16, 0, 0);
  }

  int cur = 0;
  for (int t = b; ; t += NPERS) {
    int tn = t + NPERS;
    bool hasNext = tn < NTILE;

    // ---- wait for current tile's DMA (issued a full iteration ago) ----
    asm volatile("s_waitcnt vmcnt(0)" ::: "memory");
    __syncthreads();   // implicit drain is free: vmcnt already 0

    // ---- prefetch next tile into the other buffer ----
    int bin = bi, bjn = bj;
    if (hasNext) {
      decode_tile(tn, bin, bjn);
      int nc = cur ^ 1;
      const unsigned char* Ab = zb + (((size_t)bin << 7) * DIMK);
      const unsigned char* Bb = zb + (((size_t)bjn << 7) * DIMK);
      #pragma unroll
      for (int it = 0; it < 2; ++it) {
        int L0 = (it << 9) + (wave << 6);
        __builtin_amdgcn_global_load_lds(
            (const AS_GLOBAL void*)(uintptr_t)(Ab + (size_t)(L0 + lane) * 16),
            (AS_LDS void*)(uintptr_t)(&buf[nc][(size_t)L0 * 16]), 16, 0, 0);
        __builtin_amdgcn_global_load_lds(
            (const AS_GLOBAL void*)(uintptr_t)(Bb + (size_t)(L0 + lane) * 16),
            (AS_LDS void*)(uintptr_t)(&buf[nc][16384 + (size_t)L0 * 16]), 16, 0, 0);
      }
      const char* p0 = sl_isLa ? (const char*)labels : (const char*)sq;
      const char* src = p0 + ((size_t)((sl_isB ? bjn : bin) << 7) << 2)
                           + (sl_half << 8);
      if (lane < 16)
        __builtin_amdgcn_global_load_lds(
            (const AS_GLOBAL void*)(uintptr_t)(src + lane * 16),
            (AS_LDS void*)(uintptr_t)(&sqlab[nc][wave << 8]), 16, 0, 0);
    }

    // ---- compute tile t from buf[cur] ----
    const unsigned char* ldsA = &buf[cur][0];
    const unsigned char* ldsB = &buf[cur][16384];
    const float* sqAl = (const float*)&sqlab[cur][0];
    const int*   laAl = (const int*)&sqlab[cur][512];
    const float* sqBl = (const float*)&sqlab[cur][1024];
    const int*   laBl = (const int*)&sqlab[cur][1536];

    f32x4 acc[2][4] = {};
    #pragma unroll
    for (int ks = 0; ks < 4; ++ks) {
      int so = ((((q << 2) | ks) ^ lc) << 3);        // swizzled slot offset
      long a0 = *(const long*)(ldsA + ((wm << 5)      + lc) * 128 + so);
      long a1 = *(const long*)(ldsA + ((wm << 5) + 16 + lc) * 128 + so);
      long b0 = *(const long*)(ldsB + ((wn << 6)      + lc) * 128 + so);
      long b1 = *(const long*)(ldsB + ((wn << 6) + 16 + lc) * 128 + so);
      long b2 = *(const long*)(ldsB + ((wn << 6) + 32 + lc) * 128 + so);
      long b3 = *(const long*)(ldsB + ((wn << 6) + 48 + lc) * 128 + so);
      acc[0][0] = __builtin_amdgcn_mfma_f32_16x16x32_fp8_fp8(a0, b0, acc[0][0], 0, 0, 0);
      acc[0][1] = __builtin_amdgcn_mfma_f32_16x16x32_fp8_fp8(a0, b1, acc[0][1], 0, 0, 0);
      acc[0][2] = __builtin_amdgcn_mfma_f32_16x16x32_fp8_fp8(a0, b2, acc[0][2], 0, 0, 0);
      acc[0][3] = __builtin_amdgcn_mfma_f32_16x16x32_fp8_fp8(a0, b3, acc[0][3], 0, 0, 0);
      acc[1][0] = __builtin_amdgcn_mfma_f32_16x16x32_fp8_fp8(a1, b0, acc[1][0], 0, 0, 0);
      acc[1][1] = __builtin_amdgcn_mfma_f32_16x16x32_fp8_fp8(a1, b1, acc[1][1], 0, 0, 0);
      acc[1][2] = __builtin_amdgcn_mfma_f32_16x16x32_fp8_fp8(a1, b2, acc[1][2], 0, 0, 0);
      acc[1][3] = __builtin_amdgcn_mfma_f32_16x16x32_fp8_fp8(a1, b3, acc[1][3], 0, 0, 0);
    }

    // ---- epilogue: branchless fast pass + ONE deferred vote ----
    // C/D layout: col = lane&15, row = (lane>>4)*4 + reg. If every d2 in
    // this wave's outputs >= 1: non-eq term EXACTLY 0, eq term exactly d2.
    int r0 = q << 2;
    float sn_[4]; int ln_[4];
    #pragma unroll
    for (int j = 0; j < 4; ++j) {
      int n = (wn << 6) + (j << 4) + lc;
      sn_[j] = sqBl[n]; ln_[j] = laBl[n];
    }
    float ps0 = 0.f, ps1 = 0.f, ps2 = 0.f, ps3 = 0.f;
    float mnall = 1e30f;
    #pragma unroll
    for (int i = 0; i < 2; ++i) {
      int mb = (wm << 5) + (i << 4) + r0;
      f32x4 sm4 = *(const f32x4*)&sqAl[mb];
      int4  lm4 = *(const int4*)&laAl[mb];
      #pragma unroll
      for (int j = 0; j < 4; ++j) {
        float d0  = fmaf(-2.f, acc[i][j][0], sm4[0] + sn_[j]);
        float d1  = fmaf(-2.f, acc[i][j][1], sm4[1] + sn_[j]);
        float d2_ = fmaf(-2.f, acc[i][j][2], sm4[2] + sn_[j]);
        float d3  = fmaf(-2.f, acc[i][j][3], sm4[3] + sn_[j]);
        mnall = fminf(mnall, fminf(fminf(d0, d1), fminf(d2_, d3)));
        ps0 += (lm4.x == ln_[j]) ? d0  : 0.f;
        ps1 += (lm4.y == ln_[j]) ? d1  : 0.f;
        ps2 += (lm4.z == ln_[j]) ? d2_ : 0.f;
        ps3 += (lm4.w == ln_[j]) ? d3  : 0.f;
      }
    }
    if (__builtin_expect(__any(mnall < 1.f), 0)) {
      // exact slow path (diagonal-touching waves only); acc still live
      ps0 = ps1 = ps2 = ps3 = 0.f;
      #pragma unroll
      for (int i = 0; i < 2; ++i) {
        int mb = (wm << 5) + (i << 4) + r0;
        f32x4 sm4 = *(const f32x4*)&sqAl[mb];
        int4  lm4 = *(const int4*)&laAl[mb];
        #pragma unroll
        for (int j = 0; j < 4; ++j) {
          float dc, tt;
          dc = fmaxf(fmaf(-2.f, acc[i][j][0], sm4[0] + sn_[j]), 0.f);
          tt = fmaxf(1.f - sqrtf(dc), 0.f);
          ps0 += (lm4.x == ln_[j]) ? dc : tt * tt;
          dc = fmaxf(fmaf(-2.f, acc[i][j][1], sm4[1] + sn_[j]), 0.f);
          tt = fmaxf(1.f - sqrtf(dc), 0.f);
          ps1 += (lm4.y == ln_[j]) ? dc : tt * tt;
          dc = fmaxf(fmaf(-2.f, acc[i][j][2], sm4[2] + sn_[j]), 0.f);
          tt = fmaxf(1.f - sqrtf(dc), 0.f);
          ps2 += (lm4.z == ln_[j]) ? dc : tt * tt;
          dc = fmaxf(fmaf(-2.f, acc[i][j][3], sm4[3] + sn_[j]), 0.f);
          tt = fmaxf(1.f - sqrtf(dc), 0.f);
          ps3 += (lm4.w == ln_[j]) ? dc : tt * tt;
        }
      }
    }
    float w = (bi == bj) ? 1.f : 2.f;                // symmetry weight
    psum_acc += w * ((ps0 + ps1) + (ps2 + ps3));

    if (!hasNext) break;
    bi = bin; bj = bjn; cur ^= 1;
  }

  // ---- one block reduction at kernel end ----
  psum_acc *= (1.f / (8192.f * 8192.f));             // 2^-26, exact
  #pragma unroll
  for (int off = 32; off; off >>= 1) psum_acc += __shfl_down(psum_acc, off);
  if (lane == 0) red[wave] = psum_acc;
  __syncthreads();
  if (tid == 0) {
    float s = 0.f;
    #pragma unroll
    for (int k = 0; k < 8; ++k) s += red[k];
    partials[blockIdx.x] = s;
  }
}

// Sum NPERS partials -> out[0]. One block.
__global__ __launch_bounds__(256) void reduce_kernel(
    const float* __restrict__ partials, float* __restrict__ out) {
  int tid = threadIdx.x, lane = tid & 63, wave = tid >> 6;
  float s = 0.f;
  for (int k = tid; k < NPERS; k += 256) s += partials[k];
  #pragma unroll
  for (int off = 32; off; off >>= 1) s += __shfl_down(s, off);
  __shared__ float red[4];
  if (lane == 0) red[wave] = s;
  __syncthreads();
  if (tid == 0) out[0] = red[0] + red[1] + red[2] + red[3];
}

extern "C" void kernel_launch(void* const* d_in, const int* in_sizes, int n_in,
                              void* d_out, int out_size, void* d_ws, size_t ws_size,
                              hipStream_t stream) {
  const float* z      = (const float*)d_in[0];
  const int*   labels = (const int*)d_in[1];
  float*       out    = (float*)d_out;
  unsigned char* zb   = (unsigned char*)d_ws;                        // 1 MB
  char* p = (char*)d_ws + (size_t)NROWS * DIMK;
  float* sq       = (float*)p;                                       // 32 KB
  float* partials = (float*)(p + NROWS * 4);                         // 2 KB

  prep_kernel<<<NROWS / 8, 256, 0, stream>>>(z, zb, sq);
  loss_kernel<<<NPERS, 512, 0, stream>>>(zb, sq, labels, partials);
  reduce_kernel<<<1, 256, 0, stream>>>(partials, out);
}